// Round 1
// baseline (237.343 us; speedup 1.0000x reference)
//
#include <hip/hip_runtime.h>
#include <math.h>

#define B 16
#define NAV 36
#define HIM 120
#define WIM 160
#define RH 512
#define NF 4
#define AE 37

// ---------------- workspace layout (floats) ----------------
// attn   : [B*NAV]            @ 0        (576)
// dfa    : [B*NF]             @ 576      (64)
// vf_raw : [2][B][3][12]      @ 640      (1152)
// y1     : [2][B][64][269]    @ 1792     (550912)
// pano   : [B][360][1920]     @ 552704   (11059200)
// total 11,611,904 floats = 46.5 MB

// ============ kernel 1: attn softmax + dynamic-filter MLP ============
__global__ __launch_bounds__(128) void k_head(
    const float* __restrict__ nnf, const float* __restrict__ ctx,
    const float* __restrict__ fc1w, const float* __restrict__ fc1b,
    const float* __restrict__ fc2w, const float* __restrict__ fc2b,
    float* __restrict__ attn, float* __restrict__ dfa) {
  int b = blockIdx.x;
  int t = threadIdx.x;  // 128 threads
  __shared__ float s_ctx[RH];
  __shared__ float s_v[NAV];
  __shared__ float s_hid[128];
  __shared__ float s_l[NF];
  __shared__ float s_inv[2];

  if (t < NAV) s_v[t] = nnf[b * NAV + t];
  for (int k = t; k < RH; k += 128) s_ctx[k] = ctx[b * RH + k];
  __syncthreads();

  if (t == 0) {
    float m = -1e30f;
    for (int i = 0; i < NAV; i++) m = fmaxf(m, s_v[i]);
    float s = 0.f;
    for (int i = 0; i < NAV; i++) { s_v[i] = expf(s_v[i] - m); s += s_v[i]; }
    s_inv[0] = 1.0f / s;
  }
  // hid = relu(fc1 @ ctx + b)   (runs concurrently with t0's softmax; no overlap)
  float acc = fc1b[t];
  const float* wr = fc1w + t * RH;
  for (int k = 0; k < RH; k++) acc += s_ctx[k] * wr[k];
  s_hid[t] = fmaxf(acc, 0.0f);
  __syncthreads();

  if (t < NAV) attn[b * NAV + t] = s_v[t] * s_inv[0];
  if (t < NF) {
    float a = fc2b[t];
    const float* w2 = fc2w + t * 128;
    for (int k = 0; k < 128; k++) a += s_hid[k] * w2[k];
    s_l[t] = a;
  }
  __syncthreads();
  if (t == 0) {
    float m = fmaxf(fmaxf(s_l[0], s_l[1]), fmaxf(s_l[2], s_l[3]));
    float s = 0.f;
    for (int f = 0; f < NF; f++) { s_l[f] = expf(s_l[f] - m); s += s_l[f]; }
    s_inv[1] = 1.0f / s;
  }
  __syncthreads();
  if (t < NF) dfa[b * NF + t] = s_l[t] * s_inv[1];
}

// ============ kernel 2: fused conv1 + attn-scale + dynamic conv -> pano ============
// tile: 8 rows x full width (160) of one (b, group i) plane
#define TH 8
__global__ __launch_bounds__(256) void k_conv(
    const float* __restrict__ draw, const float* __restrict__ dclip,
    const float* __restrict__ obj,
    const float* __restrict__ c1w, const float* __restrict__ c1b,
    const float* __restrict__ dynf,
    const float* __restrict__ attn, const float* __restrict__ dfa,
    float* __restrict__ pano) {
  __shared__ float s_raw[16][168];   // rows y0-4 .. y0+11, cols -4..163
  __shared__ float s_clip[16][168];
  __shared__ float s_pd[12][164];    // rows y0-2 .. y0+9, cols -2..161
  __shared__ float s_po[12][164];
  __shared__ float s_w1[50];
  __shared__ float s_k[50];

  int t = threadIdx.x;
  int bz = blockIdx.z;
  int b = bz / NAV, i = bz % NAV;
  int y0 = blockIdx.y * TH;
  const size_t plane = (size_t)(b * NAV + i) * HIM * WIM;
  const float* rawp = draw + plane;
  const float* clipp = dclip + plane;
  const float* objp = obj + plane;
  float attn_bi = attn[b * NAV + i];

  for (int idx = t; idx < 16 * 168; idx += 256) {
    int rr = idx / 168, cc = idx % 168;
    int gy = y0 - 4 + rr, gx = cc - 4;
    bool ok = (gy >= 0 && gy < HIM && gx >= 0 && gx < WIM);
    s_raw[rr][cc] = ok ? rawp[gy * WIM + gx] : 0.0f;
    s_clip[rr][cc] = ok ? clipp[gy * WIM + gx] : 0.0f;
  }
  if (t < 50) {
    s_w1[t] = c1w[i * 50 + t];
  } else if (t >= 64 && t < 114) {
    int j = t - 64;
    float a = 0.f;
    for (int f = 0; f < NF; f++) a += dfa[b * NF + f] * dynf[(f * NAV + i) * 50 + j];
    s_k[j] = a;
  }
  __syncthreads();

  float bias = c1b[i];
  for (int idx = t; idx < 12 * 164; idx += 256) {
    int r = idx / 164, c = idx % 164;
    int y = y0 - 2 + r, x = c - 2;
    float pdv = 0.0f, pov = 0.0f;
    if (y >= 0 && y < HIM && x >= 0 && x < WIM) {
      float a = bias;
#pragma unroll
      for (int ky = 0; ky < 5; ky++)
#pragma unroll
        for (int kx = 0; kx < 5; kx++) {
          a += s_raw[r + ky][c + kx] * s_w1[ky * 5 + kx];
          a += s_clip[r + ky][c + kx] * s_w1[25 + ky * 5 + kx];
        }
      pdv = a * attn_bi;
      pov = objp[y * WIM + x] * attn_bi;
    }
    s_pd[r][c] = pdv;
    s_po[r][c] = pov;
  }
  __syncthreads();

  int q = i / 12, cw = i % 12;
  float* outp = pano + (size_t)b * 360 * 1920 + (size_t)((2 - q) * HIM) * 1920 + cw * WIM;
  for (int idx = t; idx < TH * WIM; idx += 256) {
    int dy = idx / WIM, x = idx % WIM;
    float a = 0.f;
#pragma unroll
    for (int ky = 0; ky < 5; ky++)
#pragma unroll
      for (int kx = 0; kx < 5; kx++) {
        a += s_pd[dy + ky][x + kx] * s_k[ky * 5 + kx];
        a += s_po[dy + ky][x + kx] * s_k[25 + ky * 5 + kx];
      }
    outp[(size_t)(y0 + dy) * 1920 + x] = a;
  }
}

// ============ kernel 3: conv2_1 on pano (path 0) and rolled pano (path 1) ============
__global__ __launch_bounds__(256) void k_c21(
    const float* __restrict__ pano, const float* __restrict__ w21,
    const float* __restrict__ b21, float* __restrict__ y1) {
  int idx = blockIdx.x * 256 + threadIdx.x;
  if (idx >= 2 * B * 64 * 269) return;
  int ox = idx % 269;
  int r = idx / 269;
  int oy = r % 64; r /= 64;
  int b = r % B;
  int p = r / B;
  const float* pp = pano + (size_t)b * 691200;
  int shift = p ? 1760 : 0;  // roll by +160: src col = (X + 1920 - 160) mod 1920
  float acc = b21[0];
#pragma unroll
  for (int ky = 0; ky < 5; ky++) {
    const float* row = pp + (size_t)(5 * oy + 10 * ky) * 1920;
#pragma unroll
    for (int kx = 0; kx < 5; kx++) {
      int X = 7 * ox + 10 * kx + shift;
      if (X >= 1920) X -= 1920;
      acc += w21[ky * 5 + kx] * row[X];
    }
  }
  y1[idx] = acc;
}

// ============ kernel 4: avgpool(3,3)/3 -> conv2_2 -> avgpool(3,9)/3 ============
__global__ __launch_bounds__(256) void k_tail(
    const float* __restrict__ y1, const float* __restrict__ w22,
    const float* __restrict__ b22, float* __restrict__ vf_raw) {
  __shared__ float s_y2[21][90];
  __shared__ float s_y3[10][44];
  int t = threadIdx.x;
  int pb = blockIdx.x;  // p*B+b
  const float* yp = y1 + (size_t)pb * 64 * 269;
  for (int idx = t; idx < 21 * 89; idx += 256) {
    int py = idx / 89, px = idx % 89;
    float s = 0.f;
    for (int dy = 0; dy < 3; dy++)
      for (int dx = 0; dx < 3; dx++)
        s += yp[(3 * py + dy) * 269 + 3 * px + dx];
    s_y2[py][px] = s * (1.0f / 9.0f);
  }
  __syncthreads();
  for (int idx = t; idx < 10 * 43; idx += 256) {
    int qy = idx / 43, qx = idx % 43;
    float a = b22[0];
#pragma unroll
    for (int ky = 0; ky < 3; ky++)
#pragma unroll
      for (int kx = 0; kx < 3; kx++)
        a += w22[ky * 3 + kx] * s_y2[2 * qy + ky][2 * qx + 2 * kx];
    s_y3[qy][qx] = a;
  }
  __syncthreads();
  if (t < 36) {
    int uy = t / 12, ux = t % 12;
    float s = 0.f;
    for (int dy = 0; dy < 3; dy++)
      for (int dx = 0; dx < 9; dx++)
        s += s_y3[3 * uy + dy][3 * ux + dx];
    vf_raw[pb * 36 + t] = s * (1.0f / 27.0f);
  }
}

// ============ kernel 5: combine paths, flip, softmax(T=10), nav_mask ============
__global__ __launch_bounds__(64) void k_vf(
    const float* __restrict__ vf_raw, const int* __restrict__ nav_idx,
    float* __restrict__ out_vf, float* __restrict__ out_mask) {
  int b = blockIdx.x;
  int t = threadIdx.x;  // 64
  __shared__ float s_v[36];
  __shared__ float s_inv;
  if (t < 36) {
    int u = t / 12, x = t % 12;
    float v1 = vf_raw[(0 * B + b) * 36 + (2 - u) * 12 + x];
    float v2 = vf_raw[(1 * B + b) * 36 + (2 - u) * 12 + (x + 1) % 12];
    s_v[t] = 0.5f * (v1 + v2) * 0.1f;  // /TEMP
  }
  __syncthreads();
  if (t == 0) {
    float m = -1e30f;
    for (int i = 0; i < 36; i++) m = fmaxf(m, s_v[i]);
    float s = 0.f;
    for (int i = 0; i < 36; i++) { s_v[i] = expf(s_v[i] - m); s += s_v[i]; }
    s_inv = 1.0f / s;
  }
  __syncthreads();
  if (t < 36) {
    out_vf[b * 36 + t] = s_v[t] * s_inv;
    float m = 0.f;
    for (int e = 0; e < 8; e++)
      if (nav_idx[b * 8 + e] == t) m = 1.0f;
    out_mask[b * 36 + t] = m;
  }
}

// ============ kernel 6: LSTM cell ============
// block handles 8 hidden units x 4 gates x all 16 batches
__global__ __launch_bounds__(256) void k_lstm(
    const float* __restrict__ ctx, const float* __restrict__ vf,
    const float* __restrict__ dfa, const float* __restrict__ pre,
    const float* __restrict__ h0, const float* __restrict__ c0,
    const float* __restrict__ wih, const float* __restrict__ whh,
    const float* __restrict__ bih, const float* __restrict__ bhh,
    float* __restrict__ h1, float* __restrict__ c1) {
  __shared__ float s_cat[B][593];  // 589 used, padded (odd stride -> no bank conflict)
  __shared__ float s_g[32][16];
  int t = threadIdx.x;
  int u0 = blockIdx.x * 8;
  for (int idx = t; idx < B * 589; idx += 256) {
    int b = idx / 589, k = idx % 589;
    float v;
    if (k < 512) v = ctx[b * 512 + k];
    else if (k < 548) v = vf[b * 36 + (k - 512)];
    else if (k < 552) v = dfa[b * 4 + (k - 548)];
    else v = pre[b * 37 + (k - 552)];
    s_cat[b][k] = v;
  }
  __syncthreads();
  int b = t & 15;
  int s0 = t >> 4;
  for (int rep = 0; rep < 2; rep++) {
    int slot = s0 + rep * 16;
    int gate = slot >> 3, du = slot & 7;
    int j = gate * 512 + u0 + du;
    float acc = bih[j] + bhh[j];
    const float* wi = wih + (size_t)j * 589;
    for (int k = 0; k < 589; k++) acc += s_cat[b][k] * wi[k];
    const float* wh = whh + (size_t)j * 512;
    const float* hb = h0 + b * 512;
    for (int k = 0; k < 512; k++) acc += hb[k] * wh[k];
    s_g[slot][b] = acc;
  }
  __syncthreads();
  if (t < 128) {
    int bb = t & 15, du = t >> 4;
    float gi = s_g[0 + du][bb], gf = s_g[8 + du][bb];
    float gg = s_g[16 + du][bb], go = s_g[24 + du][bb];
    int u = u0 + du;
    float c_old = c0[bb * 512 + u];
    float si = 1.0f / (1.0f + expf(-gi));
    float sf = 1.0f / (1.0f + expf(-gf));
    float so = 1.0f / (1.0f + expf(-go));
    float cn = sf * c_old + si * tanhf(gg);
    h1[bb * 512 + u] = so * tanhf(cn);
    c1[bb * 512 + u] = cn;
  }
}

extern "C" void kernel_launch(void* const* d_in, const int* in_sizes, int n_in,
                              void* d_out, int out_size, void* d_ws, size_t ws_size,
                              hipStream_t stream) {
  const float* depth_raw  = (const float*)d_in[0];
  const float* depth_clip = (const float*)d_in[1];
  const float* obj_feat   = (const float*)d_in[2];
  const float* nnf        = (const float*)d_in[3];
  const float* pre        = (const float*)d_in[4];
  const float* h0         = (const float*)d_in[5];
  const float* c0         = (const float*)d_in[6];
  const float* ctx        = (const float*)d_in[7];
  const int*   nav_idx    = (const int*)d_in[8];
  const float* c1w        = (const float*)d_in[9];
  const float* c1b        = (const float*)d_in[10];
  const float* fc1w       = (const float*)d_in[11];
  const float* fc1b       = (const float*)d_in[12];
  const float* fc2w       = (const float*)d_in[13];
  const float* fc2b       = (const float*)d_in[14];
  const float* dynf       = (const float*)d_in[15];
  const float* w21        = (const float*)d_in[16];
  const float* b21        = (const float*)d_in[17];
  const float* w22        = (const float*)d_in[18];
  const float* b22        = (const float*)d_in[19];
  const float* wih        = (const float*)d_in[20];
  const float* whh        = (const float*)d_in[21];
  const float* bih        = (const float*)d_in[22];
  const float* bhh        = (const float*)d_in[23];

  float* ws = (float*)d_ws;
  float* attn   = ws;
  float* dfa    = ws + 576;
  float* vf_raw = ws + 640;
  float* y1     = ws + 1792;
  float* pano   = ws + 552704;

  float* out = (float*)d_out;
  float* out_h1   = out;
  float* out_c1   = out + 8192;
  float* out_vf   = out + 16384;
  float* out_mask = out + 16960;

  k_head<<<B, 128, 0, stream>>>(nnf, ctx, fc1w, fc1b, fc2w, fc2b, attn, dfa);
  k_conv<<<dim3(1, 15, B * NAV), 256, 0, stream>>>(depth_raw, depth_clip, obj_feat,
                                                   c1w, c1b, dynf, attn, dfa, pano);
  int n1 = 2 * B * 64 * 269;
  k_c21<<<(n1 + 255) / 256, 256, 0, stream>>>(pano, w21, b21, y1);
  k_tail<<<2 * B, 256, 0, stream>>>(y1, w22, b22, vf_raw);
  k_vf<<<B, 64, 0, stream>>>(vf_raw, nav_idx, out_vf, out_mask);
  k_lstm<<<64, 256, 0, stream>>>(ctx, out_vf, dfa, pre, h0, c0,
                                 wih, whh, bih, bhh, out_h1, out_c1);
}